// Round 2
// baseline (2963.227 us; speedup 1.0000x reference)
//
#include <hip/hip_runtime.h>

#define N_      64
#define D_      128
#define L_      3136
#define K_      64
#define TL_     64
#define GROUPS_ 12   // group 0: 5 tiles; groups 1..11: 4 tiles (49 total)

typedef __attribute__((address_space(3))) void        lds_void_t;
typedef const __attribute__((address_space(1))) void  gvoid_t;

// Fused: stage tile -> norm -> logits -> softmax -> aggregate (atomic combine)
__global__ __launch_bounds__(512, 6)
void vlad_main(const float* __restrict__ x, const float* __restrict__ w,
               float* __restrict__ vacc, float* __restrict__ asum)
{
    __shared__ __align__(16) float xs[D_][TL_];   // 32 KB, raw x tile [d][p]
    __shared__ float as[TL_][K_ + 1];             // 16.6 KB, (a*inv)[p][k]
    __shared__ float redA[8][TL_];                // 2 KB
    __shared__ float redB[8][TL_];                // 2 KB
    __shared__ float norms[TL_];                  // 256 B (clamped L2 norm per pixel)

    const int t    = threadIdx.x;
    const int lane = t & 63;
    const int wv   = __builtin_amdgcn_readfirstlane(t >> 6);   // 0..7
    const int n    = blockIdx.x / GROUPS_;
    const int g    = blockIdx.x % GROUPS_;
    const int tile0 = (g == 0) ? 0 : (4 * g + 1);
    const int tile1 = (g == 0) ? 5 : (4 * g + 5);

    float acc[16];                 // thread owns k = lane, d = wv*16 + j
#pragma unroll
    for (int j = 0; j < 16; ++j) acc[j] = 0.f;
    float asum_r = 0.f;

    const float* wrow  = w + (size_t)(wv * 8) * D_;  // 8 conv rows per wave (uniform)
    const float* xbase = x + (size_t)n * D_ * L_;

    const int dl = lane >> 4;          // 0..3 (staging row within 4-row group)
    const int pl = (lane & 15) * 4;    // 0..60 (staging pixel)
    const int dbase = wv * 16;

    for (int tile = tile0; tile < tile1; ++tile) {
        const int p0 = tile * TL_;
        __syncthreads();   // S0: previous tile's consumers done
        // ---- stage x tile: 4x global_load_lds(16B) per wave = 16 d-rows ----
#pragma unroll
        for (int it = 0; it < 4; ++it) {
            const float* gp = xbase + (size_t)(dbase + it * 4 + dl) * L_ + p0 + pl;
            __builtin_amdgcn_global_load_lds((gvoid_t*)gp,
                (lds_void_t*)&xs[dbase + it * 4][0], 16, 0, 0);
        }
        __syncthreads();   // S1: tile in LDS (vmcnt drained by barrier)
        // ---- per-pixel sumsq (pixel = lane, 16 d-rows per wave) ----
        {
            float s = 0.f;
#pragma unroll
            for (int j = 0; j < 16; ++j) {
                const float v = xs[dbase + j][lane];
                s = fmaf(v, v, s);
            }
            redA[wv][lane] = s;
        }
        __syncthreads();   // S2
        float tot = 0.f;
#pragma unroll
        for (int j = 0; j < 8; ++j) tot += redA[j][lane];
        const float nrm = fmaxf(sqrtf(tot), 1e-12f);
        const float inv = 1.f / nrm;
        if (wv == 0) norms[lane] = nrm;
        // ---- logits: pixel = lane, k = wv*8 + kk (w via wave-uniform loads) ----
        float lg[8];
#pragma unroll
        for (int kk = 0; kk < 8; ++kk) lg[kk] = 0.f;
#pragma unroll 8
        for (int d = 0; d < D_; ++d) {
            const float xv = xs[d][lane];
#pragma unroll
            for (int kk = 0; kk < 8; ++kk)
                lg[kk] = fmaf(xv, wrow[kk * D_ + d], lg[kk]);
        }
        // ---- softmax over K, no max-subtraction (|logit| <= ||w_k|| ~ 0.6) ----
        float se = 0.f;
#pragma unroll
        for (int kk = 0; kk < 8; ++kk) {
            const float e = __expf(lg[kk] * inv);
            lg[kk] = e;
            se += e;
        }
        redB[wv][lane] = se;
        __syncthreads();   // S3
        float denom = 0.f;
#pragma unroll
        for (int j = 0; j < 8; ++j) denom += redB[j][lane];
        const float sc = inv / denom;          // as = a * inv  (use raw x in agg)
#pragma unroll
        for (int kk = 0; kk < 8; ++kk) as[lane][wv * 8 + kk] = lg[kk] * sc;
        __syncthreads();   // S4: a ready
        // ---- aggregation: thread owns (k = lane, d = wv*16 + j) ----
        for (int p = 0; p < TL_; p += 4) {
            const float a0 = as[p + 0][lane];
            const float a1 = as[p + 1][lane];
            const float a2 = as[p + 2][lane];
            const float a3 = as[p + 3][lane];
            if (wv == 0) {   // recover raw sum(a) for the centroid term
                asum_r += a0 * norms[p + 0] + a1 * norms[p + 1]
                        + a2 * norms[p + 2] + a3 * norms[p + 3];
            }
#pragma unroll
            for (int j = 0; j < 16; ++j) {
                const float4 xv = *reinterpret_cast<const float4*>(&xs[dbase + j][p]);
                acc[j] = fmaf(a0, xv.x, acc[j]);
                acc[j] = fmaf(a1, xv.y, acc[j]);
                acc[j] = fmaf(a2, xv.z, acc[j]);
                acc[j] = fmaf(a3, xv.w, acc[j]);
            }
        }
    }
    // ---- commit partials (12 adders per address, L2 atomics) ----
    float* dst = vacc + ((size_t)n * K_ + lane) * D_ + dbase;
#pragma unroll
    for (int j = 0; j < 16; ++j) atomicAdd(dst + j, acc[j]);
    if (wv == 0) atomicAdd(asum + n * K_ + lane, asum_r);
}

// Finalize: v = acc - asum*c; intra-normalize over d; global normalize over K*D
__global__ __launch_bounds__(256)
void vlad_fin(const float* __restrict__ vacc, const float* __restrict__ asum,
              const float* __restrict__ cent, float* __restrict__ out)
{
    __shared__ float sred[4];
    const int t = threadIdx.x;
    const int n = blockIdx.x;
    const int k = t >> 2;      // 0..63
    const int q = t & 3;       // d-chunk 0..3

    const float a = asum[n * K_ + k];
    const float* src = vacc + ((size_t)n * K_ + k) * D_ + q * 32;
    const float* cc  = cent + (size_t)k * D_ + q * 32;

    float v[32];
    float ss = 0.f;
#pragma unroll
    for (int j = 0; j < 32; ++j) {
        const float val = src[j] - a * cc[j];
        v[j] = val;
        ss = fmaf(val, val, ss);
    }
    ss += __shfl_xor(ss, 1);
    ss += __shfl_xor(ss, 2);
    const float inv1 = 1.f / fmaxf(sqrtf(ss), 1e-12f);
    float gs = 0.f;
#pragma unroll
    for (int j = 0; j < 32; ++j) { v[j] *= inv1; gs = fmaf(v[j], v[j], gs); }
#pragma unroll
    for (int off = 1; off < 64; off <<= 1) gs += __shfl_xor(gs, off);
    const int wv = t >> 6;
    if ((t & 63) == 0) sred[wv] = gs;
    __syncthreads();
    const float tot = sred[0] + sred[1] + sred[2] + sred[3];
    const float inv2 = 1.f / fmaxf(sqrtf(tot), 1e-12f);
    float* dst = out + (size_t)n * (K_ * D_) + (size_t)k * D_ + q * 32;
#pragma unroll
    for (int j = 0; j < 32; ++j) dst[j] = v[j] * inv2;
}

extern "C" void kernel_launch(void* const* d_in, const int* in_sizes, int n_in,
                              void* d_out, int out_size, void* d_ws, size_t ws_size,
                              hipStream_t stream)
{
    const float* x = (const float*)d_in[0];   // [N, D, H, W]
    const float* w = (const float*)d_in[1];   // [K, D]
    const float* c = (const float*)d_in[2];   // [K, D]
    float* out  = (float*)d_out;              // [N, K*D]
    float* vacc = (float*)d_ws;                         // N*K*D
    float* asum = vacc + (size_t)N_ * K_ * D_;          // N*K

    const size_t zbytes = ((size_t)N_ * K_ * D_ + (size_t)N_ * K_) * sizeof(float);
    hipMemsetAsync(d_ws, 0, zbytes, stream);

    vlad_main<<<dim3(N_ * GROUPS_), dim3(512), 0, stream>>>(x, w, vacc, asum);
    vlad_fin<<<dim3(N_), dim3(256), 0, stream>>>(vacc, asum, c, out);
}

// Round 3
// 2939.661 us; speedup vs baseline: 1.0080x; 1.0080x over previous
//
#include <hip/hip_runtime.h>

#define N_      64
#define D_      128
#define L_      3136
#define K_      64
#define TL_     64
#define GROUPS_ 12   // group 0: 5 tiles; groups 1..11: 4 tiles (49 total)

typedef __attribute__((address_space(3))) void        lds_void_t;
typedef const __attribute__((address_space(1))) void  gvoid_t;

// Fused: stage tile -> norm -> logits -> softmax -> aggregate (atomic combine)
// launch_bounds(512, 2): VGPR budget ~128. Occupancy is LDS-bound (53.7 KB ->
// 3 blocks/CU = 24 waves/CU) regardless; requesting 6 waves/EU in r2 cut the
// VGPR budget to 40 and spilled (9.7 GB scratch traffic, 8x regression).
__global__ __launch_bounds__(512, 2)
void vlad_main(const float* __restrict__ x, const float* __restrict__ w,
               float* __restrict__ vacc, float* __restrict__ asum)
{
    __shared__ __align__(16) float xs[D_][TL_];   // 32 KB, raw x tile [d][p]
    __shared__ float as[TL_][K_ + 1];             // 16.6 KB, (a*inv)[p][k]
    __shared__ float redA[8][TL_];                // 2 KB
    __shared__ float redB[8][TL_];                // 2 KB
    __shared__ float norms[TL_];                  // 256 B (clamped L2 norm per pixel)

    const int t    = threadIdx.x;
    const int lane = t & 63;
    const int wv   = __builtin_amdgcn_readfirstlane(t >> 6);   // 0..7
    const int n    = blockIdx.x / GROUPS_;
    const int g    = blockIdx.x % GROUPS_;
    const int tile0 = (g == 0) ? 0 : (4 * g + 1);
    const int tile1 = (g == 0) ? 5 : (4 * g + 5);

    float acc[16];                 // thread owns k = lane, d = wv*16 + j
#pragma unroll
    for (int j = 0; j < 16; ++j) acc[j] = 0.f;
    float asum_r = 0.f;

    const float* wrow  = w + (size_t)(wv * 8) * D_;  // 8 conv rows per wave (uniform)
    const float* xbase = x + (size_t)n * D_ * L_;

    const int dl = lane >> 4;          // 0..3 (staging row within 4-row group)
    const int pl = (lane & 15) * 4;    // 0..60 (staging pixel)
    const int dbase = wv * 16;

    for (int tile = tile0; tile < tile1; ++tile) {
        const int p0 = tile * TL_;
        __syncthreads();   // S0: previous tile's consumers done
        // ---- stage x tile: 4x global_load_lds(16B) per wave = 16 d-rows ----
#pragma unroll
        for (int it = 0; it < 4; ++it) {
            const float* gp = xbase + (size_t)(dbase + it * 4 + dl) * L_ + p0 + pl;
            __builtin_amdgcn_global_load_lds((gvoid_t*)gp,
                (lds_void_t*)&xs[dbase + it * 4][0], 16, 0, 0);
        }
        __syncthreads();   // S1: tile in LDS (vmcnt drained by barrier)
        // ---- per-pixel sumsq (pixel = lane, 16 d-rows per wave) ----
        {
            float s = 0.f;
#pragma unroll
            for (int j = 0; j < 16; ++j) {
                const float v = xs[dbase + j][lane];
                s = fmaf(v, v, s);
            }
            redA[wv][lane] = s;
        }
        __syncthreads();   // S2
        float tot = 0.f;
#pragma unroll
        for (int j = 0; j < 8; ++j) tot += redA[j][lane];
        const float nrm = fmaxf(sqrtf(tot), 1e-12f);
        const float inv = 1.f / nrm;
        if (wv == 0) norms[lane] = nrm;
        // ---- logits: pixel = lane, k = wv*8 + kk (w via wave-uniform loads) ----
        float lg[8];
#pragma unroll
        for (int kk = 0; kk < 8; ++kk) lg[kk] = 0.f;
#pragma unroll 8
        for (int d = 0; d < D_; ++d) {
            const float xv = xs[d][lane];
#pragma unroll
            for (int kk = 0; kk < 8; ++kk)
                lg[kk] = fmaf(xv, wrow[kk * D_ + d], lg[kk]);
        }
        // ---- softmax over K, no max-subtraction (|logit| <= ||w_k|| ~ 0.6) ----
        float se = 0.f;
#pragma unroll
        for (int kk = 0; kk < 8; ++kk) {
            const float e = __expf(lg[kk] * inv);
            lg[kk] = e;
            se += e;
        }
        redB[wv][lane] = se;
        __syncthreads();   // S3
        float denom = 0.f;
#pragma unroll
        for (int j = 0; j < 8; ++j) denom += redB[j][lane];
        const float sc = inv / denom;          // as = a * inv  (use raw x in agg)
#pragma unroll
        for (int kk = 0; kk < 8; ++kk) as[lane][wv * 8 + kk] = lg[kk] * sc;
        __syncthreads();   // S4: a ready
        // ---- aggregation: thread owns (k = lane, d = wv*16 + j) ----
        for (int p = 0; p < TL_; p += 4) {
            const float a0 = as[p + 0][lane];
            const float a1 = as[p + 1][lane];
            const float a2 = as[p + 2][lane];
            const float a3 = as[p + 3][lane];
            if (wv == 0) {   // recover raw sum(a) for the centroid term
                asum_r += a0 * norms[p + 0] + a1 * norms[p + 1]
                        + a2 * norms[p + 2] + a3 * norms[p + 3];
            }
#pragma unroll
            for (int j = 0; j < 16; ++j) {
                const float4 xv = *reinterpret_cast<const float4*>(&xs[dbase + j][p]);
                acc[j] = fmaf(a0, xv.x, acc[j]);
                acc[j] = fmaf(a1, xv.y, acc[j]);
                acc[j] = fmaf(a2, xv.z, acc[j]);
                acc[j] = fmaf(a3, xv.w, acc[j]);
            }
        }
    }
    // ---- commit partials (12 adders per address, L2 atomics) ----
    float* dst = vacc + ((size_t)n * K_ + lane) * D_ + dbase;
#pragma unroll
    for (int j = 0; j < 16; ++j) atomicAdd(dst + j, acc[j]);
    if (wv == 0) atomicAdd(asum + n * K_ + lane, asum_r);
}

// Finalize: v = acc - asum*c; intra-normalize over d; global normalize over K*D
__global__ __launch_bounds__(256)
void vlad_fin(const float* __restrict__ vacc, const float* __restrict__ asum,
              const float* __restrict__ cent, float* __restrict__ out)
{
    __shared__ float sred[4];
    const int t = threadIdx.x;
    const int n = blockIdx.x;
    const int k = t >> 2;      // 0..63
    const int q = t & 3;       // d-chunk 0..3

    const float a = asum[n * K_ + k];
    const float* src = vacc + ((size_t)n * K_ + k) * D_ + q * 32;
    const float* cc  = cent + (size_t)k * D_ + q * 32;

    float v[32];
    float ss = 0.f;
#pragma unroll
    for (int j = 0; j < 32; ++j) {
        const float val = src[j] - a * cc[j];
        v[j] = val;
        ss = fmaf(val, val, ss);
    }
    ss += __shfl_xor(ss, 1);
    ss += __shfl_xor(ss, 2);
    const float inv1 = 1.f / fmaxf(sqrtf(ss), 1e-12f);
    float gs = 0.f;
#pragma unroll
    for (int j = 0; j < 32; ++j) { v[j] *= inv1; gs = fmaf(v[j], v[j], gs); }
#pragma unroll
    for (int off = 1; off < 64; off <<= 1) gs += __shfl_xor(gs, off);
    const int wv = t >> 6;
    if ((t & 63) == 0) sred[wv] = gs;
    __syncthreads();
    const float tot = sred[0] + sred[1] + sred[2] + sred[3];
    const float inv2 = 1.f / fmaxf(sqrtf(tot), 1e-12f);
    float* dst = out + (size_t)n * (K_ * D_) + (size_t)k * D_ + q * 32;
#pragma unroll
    for (int j = 0; j < 32; ++j) dst[j] = v[j] * inv2;
}

extern "C" void kernel_launch(void* const* d_in, const int* in_sizes, int n_in,
                              void* d_out, int out_size, void* d_ws, size_t ws_size,
                              hipStream_t stream)
{
    const float* x = (const float*)d_in[0];   // [N, D, H, W]
    const float* w = (const float*)d_in[1];   // [K, D]
    const float* c = (const float*)d_in[2];   // [K, D]
    float* out  = (float*)d_out;              // [N, K*D]
    float* vacc = (float*)d_ws;                         // N*K*D
    float* asum = vacc + (size_t)N_ * K_ * D_;          // N*K

    const size_t zbytes = ((size_t)N_ * K_ * D_ + (size_t)N_ * K_) * sizeof(float);
    hipMemsetAsync(d_ws, 0, zbytes, stream);

    vlad_main<<<dim3(N_ * GROUPS_), dim3(512), 0, stream>>>(x, w, vacc, asum);
    vlad_fin<<<dim3(N_), dim3(256), 0, stream>>>(vacc, asum, c, out);
}

// Round 4
// 406.233 us; speedup vs baseline: 7.2944x; 7.2364x over previous
//
#include <hip/hip_runtime.h>

#define N_      64
#define D_      128
#define L_      3136
#define K_      64
#define TL_     64
#define GROUPS_ 12   // group 0: 5 tiles; groups 1..11: 4 tiles (49 total)

// Fused: stage tile -> sumsq -> logits -> softmax(folded norm) -> aggregate.
// 256 threads / 4 waves (proven 68-VGPR no-spill shape from r1).
// 50.9 KB LDS -> 3 blocks/CU; grid 768 = exactly 3/CU.
// r2/r3 lesson: 512-thread variant spills at any launch_bounds (demand >128);
// spill traffic (8-10 GB scratch) was the entire regression.
__global__ __launch_bounds__(256, 3)
void vlad_main(const float* __restrict__ x, const float* __restrict__ w,
               float* __restrict__ vacc, float* __restrict__ asum)
{
    __shared__ __align__(16) float xs[D_][TL_];   // 32 KB, raw x tile [d][p]
    __shared__ float as[TL_][K_ + 1];             // 16.6 KB, (a*inv)[p][k]
    __shared__ float redA[4][TL_];                // 1 KB
    __shared__ float redB[4][TL_];                // 1 KB
    __shared__ float norms[TL_];                  // 256 B

    const int t    = threadIdx.x;
    const int lane = t & 63;
    const int wv   = __builtin_amdgcn_readfirstlane(t >> 6);  // 0..3 (uniform)
    const int n    = blockIdx.x / GROUPS_;
    const int g    = blockIdx.x % GROUPS_;
    const int tile0 = (g == 0) ? 0 : (4 * g + 1);
    const int tile1 = (g == 0) ? 5 : (4 * g + 5);

    float acc[32];                 // thread owns k = lane, d = wv*32 + j
#pragma unroll
    for (int j = 0; j < 32; ++j) acc[j] = 0.f;
    float asum_r = 0.f;

    const int dload = (t >> 4);        // 0..15
    const int pload = (t & 15) * 4;    // 0..60 step 4
    const int dbase = wv * 32;

    const float* wrow  = w + (size_t)(wv * 16) * D_;  // 16 conv rows per wave (uniform)
    const float* xbase = x + (size_t)n * D_ * L_;

    for (int tile = tile0; tile < tile1; ++tile) {
        const int p0 = tile * TL_;
        __syncthreads();   // S0: previous tile's consumers done
        // ---- load x tile (coalesced float4, 16B x 2048) ----
#pragma unroll
        for (int i = 0; i < 8; ++i) {
            const int d = i * 16 + dload;
            const float4 v = *reinterpret_cast<const float4*>(
                xbase + (size_t)d * L_ + p0 + pload);
            *reinterpret_cast<float4*>(&xs[d][pload]) = v;
        }
        __syncthreads();   // S1: tile loaded
        // ---- per-pixel sumsq (pixel = lane, 32 d-rows per wave) ----
        {
            float s = 0.f;
#pragma unroll
            for (int j = 0; j < 32; ++j) {
                const float v = xs[dbase + j][lane];
                s = fmaf(v, v, s);
            }
            redA[wv][lane] = s;
        }
        __syncthreads();   // S2
        const float tot = redA[0][lane] + redA[1][lane] + redA[2][lane] + redA[3][lane];
        const float nrm = fmaxf(sqrtf(tot), 1e-12f);
        const float inv = 1.f / nrm;
        if (wv == 0) norms[lane] = nrm;
        // ---- logits on RAW x: pixel = lane, k = wv*16 + kk (w wave-uniform s_loads) ----
        float lg[16];
#pragma unroll
        for (int kk = 0; kk < 16; ++kk) lg[kk] = 0.f;
#pragma unroll 4
        for (int d = 0; d < D_; ++d) {
            const float xv = xs[d][lane];
#pragma unroll
            for (int kk = 0; kk < 16; ++kk)
                lg[kk] = fmaf(xv, wrow[kk * D_ + d], lg[kk]);
        }
        // ---- softmax over K with norm folded (|logit*inv| <= ||w_k|| ~ 0.6) ----
        float se = 0.f;
#pragma unroll
        for (int kk = 0; kk < 16; ++kk) {
            const float e = __expf(lg[kk] * inv);
            lg[kk] = e;
            se += e;
        }
        redB[wv][lane] = se;
        __syncthreads();   // S3
        const float denom = redB[0][lane] + redB[1][lane] + redB[2][lane] + redB[3][lane];
        const float sc = inv / denom;          // as = a * inv  (agg uses raw x)
#pragma unroll
        for (int kk = 0; kk < 16; ++kk) as[lane][wv * 16 + kk] = lg[kk] * sc;
        __syncthreads();   // S4: a ready
        // ---- aggregation: thread owns (k = lane, d = wv*32 + j) ----
        for (int p = 0; p < TL_; p += 4) {
            const float a0 = as[p + 0][lane];
            const float a1 = as[p + 1][lane];
            const float a2 = as[p + 2][lane];
            const float a3 = as[p + 3][lane];
            if (wv == 0) {   // recover raw sum(a) for the centroid term
                asum_r += a0 * norms[p + 0] + a1 * norms[p + 1]
                        + a2 * norms[p + 2] + a3 * norms[p + 3];
            }
#pragma unroll
            for (int j = 0; j < 32; ++j) {
                const float4 xv = *reinterpret_cast<const float4*>(&xs[dbase + j][p]);
                acc[j] = fmaf(a0, xv.x, acc[j]);
                acc[j] = fmaf(a1, xv.y, acc[j]);
                acc[j] = fmaf(a2, xv.z, acc[j]);
                acc[j] = fmaf(a3, xv.w, acc[j]);
            }
        }
    }
    // ---- commit partials (12 adders per address, L2 atomics) ----
    float* dst = vacc + ((size_t)n * K_ + lane) * D_ + dbase;
#pragma unroll
    for (int j = 0; j < 32; ++j) atomicAdd(dst + j, acc[j]);
    if (wv == 0) atomicAdd(asum + n * K_ + lane, asum_r);
}

// Finalize: v = acc - asum*c; intra-normalize over d; global normalize over K*D
__global__ __launch_bounds__(256)
void vlad_fin(const float* __restrict__ vacc, const float* __restrict__ asum,
              const float* __restrict__ cent, float* __restrict__ out)
{
    __shared__ float sred[4];
    const int t = threadIdx.x;
    const int n = blockIdx.x;
    const int k = t >> 2;      // 0..63
    const int q = t & 3;       // d-chunk 0..3

    const float a = asum[n * K_ + k];
    const float* src = vacc + ((size_t)n * K_ + k) * D_ + q * 32;
    const float* cc  = cent + (size_t)k * D_ + q * 32;

    float v[32];
    float ss = 0.f;
#pragma unroll
    for (int j = 0; j < 32; ++j) {
        const float val = src[j] - a * cc[j];
        v[j] = val;
        ss = fmaf(val, val, ss);
    }
    ss += __shfl_xor(ss, 1);
    ss += __shfl_xor(ss, 2);
    const float inv1 = 1.f / fmaxf(sqrtf(ss), 1e-12f);
    float gs = 0.f;
#pragma unroll
    for (int j = 0; j < 32; ++j) { v[j] *= inv1; gs = fmaf(v[j], v[j], gs); }
#pragma unroll
    for (int off = 1; off < 64; off <<= 1) gs += __shfl_xor(gs, off);
    const int wv = t >> 6;
    if ((t & 63) == 0) sred[wv] = gs;
    __syncthreads();
    const float tot = sred[0] + sred[1] + sred[2] + sred[3];
    const float inv2 = 1.f / fmaxf(sqrtf(tot), 1e-12f);
    float* dst = out + (size_t)n * (K_ * D_) + (size_t)k * D_ + q * 32;
#pragma unroll
    for (int j = 0; j < 32; ++j) dst[j] = v[j] * inv2;
}

extern "C" void kernel_launch(void* const* d_in, const int* in_sizes, int n_in,
                              void* d_out, int out_size, void* d_ws, size_t ws_size,
                              hipStream_t stream)
{
    const float* x = (const float*)d_in[0];   // [N, D, H, W]
    const float* w = (const float*)d_in[1];   // [K, D]
    const float* c = (const float*)d_in[2];   // [K, D]
    float* out  = (float*)d_out;              // [N, K*D]
    float* vacc = (float*)d_ws;                         // N*K*D
    float* asum = vacc + (size_t)N_ * K_ * D_;          // N*K

    const size_t zbytes = ((size_t)N_ * K_ * D_ + (size_t)N_ * K_) * sizeof(float);
    hipMemsetAsync(d_ws, 0, zbytes, stream);

    vlad_main<<<dim3(N_ * GROUPS_), dim3(256), 0, stream>>>(x, w, vacc, asum);
    vlad_fin<<<dim3(N_), dim3(256), 0, stream>>>(vacc, asum, c, out);
}

// Round 5
// 56.486 us; speedup vs baseline: 52.4595x; 7.1917x over previous
//
#include <hip/hip_runtime.h>

#define N_   64
#define D_   128
#define L_   3136
#define K_   64
#define TL_  64
#define NG_  8      // pixel groups per image -> grid = 64*8 = 512 blocks
// tiles per group: g==0 -> 7, else 6 (7 + 7*6 = 49 tiles of 64 pixels)

typedef short  short8  __attribute__((ext_vector_type(8)));
typedef short  short4v __attribute__((ext_vector_type(4)));
typedef float  f32x16  __attribute__((ext_vector_type(16)));

static __device__ __forceinline__ unsigned short f2bf(float f) {
    unsigned u = __float_as_uint(f);                       // RNE f32 -> bf16 bits
    return (unsigned short)((u + 0x7FFFu + ((u >> 16) & 1u)) >> 16);
}
static __device__ __forceinline__ float bf2f(short s) {
    return __uint_as_float(((unsigned)(unsigned short)s) << 16);
}

// Full-MFMA fused NetVLAD main: stage X (bf16, two LDS layouts) -> logits via
// mfma (W-frags in regs) -> softmax (fp32, folded norm, no max-sub:
// |logit*inv| <= ||w_k|| ~ 0.57) -> A_s bf16 -> aggregation via mfma, C-frags
// persist across tiles. Partials committed non-atomically per group slab.
// k-ordering note: A/B frag k-element placement only needs A<->B consistency
// (bijective relabeling cancels in the contraction); m/n = lane&31 is fixed HW.
__global__ __launch_bounds__(256, 3)
void vlad_main(const float* __restrict__ x, const float* __restrict__ w,
               float* __restrict__ vout, float* __restrict__ aout,
               int vstride, int astride)   // vstride==0 => atomic accumulate path
{
    __shared__ short L1[TL_ * D_];     // [l][dk] bf16, byte-swizzled ^((l&15)<<4), 16KB
    __shared__ short L2[D_ * TL_];     // [dk][l] bf16, byte-swizzled ^((dk&7)<<4), 16KB
    __shared__ short As[K_ * 72];      // [k][p] bf16 a*inv, row pad 72, 9KB
    __shared__ float red_ss[16][68];   // sumsq partials
    __shared__ float inv_lds[TL_], nrm_lds[TL_];
    __shared__ float dred[4][32];      // softmax denominator exchange

    const int t    = threadIdx.x;
    const int lane = t & 63;
    const int wv   = __builtin_amdgcn_readfirstlane(t >> 6);  // 0..3
    const int n    = blockIdx.x / NG_;
    const int g    = blockIdx.x % NG_;
    const int tile0 = (g == 0) ? 0 : (7 + 6 * (g - 1));
    const int ntile = (g == 0) ? 7 : 6;

    const int Mt = wv & 1;     // cluster-half (M) for both phases
    const int lg = lane >> 5;  // k-element group (0/1)
    const int lm = lane & 31;

    char* L1b = (char*)L1;
    char* L2b = (char*)L2;
    char* Asb = (char*)As;

    // ---- W fragments, loop-invariant, kept in 32 VGPRs ----
    short8 wf[8];
#pragma unroll
    for (int ks = 0; ks < 8; ++ks) {
        const float* wp = w + (size_t)(32 * Mt + lm) * D_ + 16 * ks + 8 * lg;
        const float4 wa = *(const float4*)wp;
        const float4 wb = *(const float4*)(wp + 4);
        short8 f;
        f[0]=f2bf(wa.x); f[1]=f2bf(wa.y); f[2]=f2bf(wa.z); f[3]=f2bf(wa.w);
        f[4]=f2bf(wb.x); f[5]=f2bf(wb.y); f[6]=f2bf(wb.z); f[7]=f2bf(wb.w);
        wf[ks] = f;
    }

    f32x16 acc0 = {0};   // V[k][d] C-frag, d-tile 2*(wv>>1)
    f32x16 acc1 = {0};   // d-tile 2*(wv>>1)+1
    float asum_acc = 0.f;

    const int q  = t >> 4;          // staging: d-rows 8q..8q+7
    const int l0 = (t & 15) * 4;    // staging: 4 pixels
    const float* xb = x + (size_t)n * D_ * L_;

    for (int ti = 0; ti < ntile; ++ti) {
        const int p0 = (tile0 + ti) * TL_;
        __syncthreads();  // bar0: prior tile's L2/As consumers done
        // ---- stage: 8 float4 (8 d x 4 l) -> sumsq + L1 + L2 ----
        float4 v[8];
#pragma unroll
        for (int r = 0; r < 8; ++r)
            v[r] = *(const float4*)(xb + (size_t)(8 * q + r) * L_ + p0 + l0);
#pragma unroll
        for (int j = 0; j < 4; ++j) {
            float s = 0.f;
#pragma unroll
            for (int r = 0; r < 8; ++r) {
                const float val = (&v[r].x)[j];
                s = fmaf(val, val, s);
            }
            red_ss[q][l0 + j] = s;
        }
#pragma unroll
        for (int j = 0; j < 4; ++j) {   // L1: per pixel, 8 consecutive dk (b128)
            const int l = l0 + j;
            short8 f;
#pragma unroll
            for (int r = 0; r < 8; ++r) f[r] = f2bf((&v[r].x)[j]);
            *(short8*)(L1b + l * 256 + ((16 * q) ^ ((l & 15) << 4))) = f;
        }
#pragma unroll
        for (int r = 0; r < 8; ++r) {   // L2: per d, 4 consecutive l (b64)
            const int d = 8 * q + r;
            short4v f;
#pragma unroll
            for (int j = 0; j < 4; ++j) f[j] = f2bf((&v[r].x)[j]);
            *(short4v*)(L2b + d * 128 + ((l0 * 2) ^ ((d & 7) << 4))) = f;
        }
        __syncthreads();  // bar1: tile staged
        if (t < TL_) {
            float ss = 0.f;
#pragma unroll
            for (int qq = 0; qq < 16; ++qq) ss += red_ss[qq][t];
            const float nr = fmaxf(sqrtf(ss), 1e-12f);
            nrm_lds[t] = nr;
            inv_lds[t] = 1.f / nr;
        }
        // ---- phase 1: R = W * X (quadrant Mt x Nt), contraction dk=128 ----
        f32x16 r1 = {0};
        {
            const int l = 32 * (wv >> 1) + lm;   // pixel = col = lane&31
            const int rowoff = l * 256;
            const int swz = (l & 15) << 4;
#pragma unroll
            for (int ks = 0; ks < 8; ++ks) {
                const short8 bfr = *(short8*)(L1b + rowoff + (((16 * ks + 8 * lg) * 2) ^ swz));
                r1 = __builtin_amdgcn_mfma_f32_32x32x16_bf16(wf[ks], bfr, r1, 0, 0, 0);
            }
        }
        __syncthreads();  // bar2: inv ready
        // ---- softmax over k (no max-sub; bounded logits) ----
        const float invp = inv_lds[32 * (wv >> 1) + lm];
        float e[16];
        float s = 0.f;
#pragma unroll
        for (int r = 0; r < 16; ++r) { e[r] = __expf(r1[r] * invp); s += e[r]; }
        s += __shfl_xor(s, 32);              // combine the two k-halves per pixel
        if (lane < 32) dred[wv][lm] = s;
        __syncthreads();  // bar3
        const float denom = dred[wv][lm] + dred[wv ^ 1][lm];   // cross-Mt partner
        const float sc = invp / denom;       // A_s = a * inv (agg uses raw X)
#pragma unroll
        for (int r = 0; r < 16; ++r) {
            const int k = 32 * Mt + (r & 3) + 8 * (r >> 2) + 4 * lg;
            ((short*)Asb)[k * 72 + 32 * (wv >> 1) + lm] = (short)f2bf(e[r] * sc);
        }
        __syncthreads();  // bar4: A_s ready
        // ---- phase 2: V += A_s * X^T, contraction l=64 ----
        {
            short8 af[4];
            const int arow = (32 * Mt + lm) * 144;
#pragma unroll
            for (int ks = 0; ks < 4; ++ks)
                af[ks] = *(short8*)(Asb + arow + (16 * ks + 8 * lg) * 2);
#pragma unroll
            for (int nt = 0; nt < 2; ++nt) {
                const int dk = 32 * (2 * (wv >> 1) + nt) + lm;  // d = col = lane&31
                const int rowoff = dk * 128;
                const int swz = (dk & 7) << 4;
                f32x16 a = (nt == 0) ? acc0 : acc1;
#pragma unroll
                for (int ks = 0; ks < 4; ++ks) {
                    const short8 bfr = *(short8*)(L2b + rowoff + (((16 * ks + 8 * lg) * 2) ^ swz));
                    a = __builtin_amdgcn_mfma_f32_32x32x16_bf16(af[ks], bfr, a, 0, 0, 0);
                }
                if (nt == 0) acc0 = a; else acc1 = a;
            }
        }
        // ---- asum partial: asum[k] += sum_l A_s[k][l]*nrm[l] (balanced) ----
        {
            const int k  = 16 * wv + (lane & 15);
            const int c4 = lane >> 4;                 // l-chunk 16*c4
            const char* ap = Asb + k * 144 + c4 * 32;
            const short8 a0 = *(short8*)ap;
            const short8 a1 = *(short8*)(ap + 16);
            float ps = 0.f;
#pragma unroll
            for (int i = 0; i < 8; ++i) {
                ps = fmaf(bf2f(a0[i]), nrm_lds[16 * c4 + i],     ps);
                ps = fmaf(bf2f(a1[i]), nrm_lds[16 * c4 + 8 + i], ps);
            }
            ps += __shfl_xor(ps, 16);
            ps += __shfl_xor(ps, 32);
            asum_acc += ps;
        }
    }
    // ---- commit: per-group slab (plain stores) or atomic fallback ----
    {
        const int dbase0 = 32 * (2 * (wv >> 1));
        float* vb = vstride ? (vout + (size_t)g * vstride) : vout;
#pragma unroll
        for (int r = 0; r < 16; ++r) {
            const int k = 32 * Mt + (r & 3) + 8 * (r >> 2) + 4 * lg;
            float* row = vb + ((size_t)n * K_ + k) * D_ + lm;
            if (vstride) {
                row[dbase0]      = acc0[r];
                row[dbase0 + 32] = acc1[r];
            } else {
                atomicAdd(&row[dbase0],      acc0[r]);
                atomicAdd(&row[dbase0 + 32], acc1[r]);
            }
        }
        if (lane < 16) {
            const int k = 16 * wv + lane;
            if (astride) aout[(size_t)g * astride + n * K_ + k] = asum_acc;
            else atomicAdd(&aout[n * K_ + k], asum_acc);
        }
    }
}

// Finalize: sum partials; v = V - asum*c; intra-norm over d; global norm.
__global__ __launch_bounds__(256)
void vlad_fin(const float* __restrict__ vacc, const float* __restrict__ asum,
              const float* __restrict__ cent, float* __restrict__ out, int npart)
{
    __shared__ float sred[4];
    const int t = threadIdx.x;
    const int n = blockIdx.x;
    const int k = t >> 2;
    const int qq = t & 3;

    float a = 0.f;
    for (int g = 0; g < npart; ++g) a += asum[(size_t)g * (N_ * K_) + n * K_ + k];

    const float* cc = cent + (size_t)k * D_ + qq * 32;
    const size_t off = ((size_t)n * K_ + k) * D_ + qq * 32;
    float v[32];
#pragma unroll
    for (int j = 0; j < 32; ++j) v[j] = 0.f;
    for (int g = 0; g < npart; ++g) {
        const float* src = vacc + (size_t)g * ((size_t)N_ * K_ * D_) + off;
#pragma unroll
        for (int j = 0; j < 32; ++j) v[j] += src[j];
    }
    float ss = 0.f;
#pragma unroll
    for (int j = 0; j < 32; ++j) {
        v[j] = v[j] - a * cc[j];
        ss = fmaf(v[j], v[j], ss);
    }
    ss += __shfl_xor(ss, 1);
    ss += __shfl_xor(ss, 2);
    const float inv1 = 1.f / fmaxf(sqrtf(ss), 1e-12f);
    float gs = 0.f;
#pragma unroll
    for (int j = 0; j < 32; ++j) { v[j] *= inv1; gs = fmaf(v[j], v[j], gs); }
#pragma unroll
    for (int off2 = 1; off2 < 64; off2 <<= 1) gs += __shfl_xor(gs, off2);
    const int wv = t >> 6;
    if ((t & 63) == 0) sred[wv] = gs;
    __syncthreads();
    const float tot = sred[0] + sred[1] + sred[2] + sred[3];
    const float inv2 = 1.f / fmaxf(sqrtf(tot), 1e-12f);
    float* dst = out + (size_t)n * (K_ * D_) + (size_t)k * D_ + qq * 32;
#pragma unroll
    for (int j = 0; j < 32; ++j) dst[j] = v[j] * inv2;
}

extern "C" void kernel_launch(void* const* d_in, const int* in_sizes, int n_in,
                              void* d_out, int out_size, void* d_ws, size_t ws_size,
                              hipStream_t stream)
{
    const float* x = (const float*)d_in[0];   // [N, D, H, W]
    const float* w = (const float*)d_in[1];   // [K, D]
    const float* c = (const float*)d_in[2];   // [K, D]
    float* out = (float*)d_out;               // [N, K*D]

    const size_t vs  = (size_t)N_ * K_ * D_;  // 524288
    const size_t as_ = (size_t)N_ * K_;       // 4096
    const size_t need = (NG_ * vs + NG_ * as_) * sizeof(float);  // ~16.9 MB
    float* vacc = (float*)d_ws;

    if (ws_size >= need) {
        float* ap = vacc + NG_ * vs;
        vlad_main<<<dim3(N_ * NG_), dim3(256), 0, stream>>>(x, w, vacc, ap,
                                                            (int)vs, (int)as_);
        vlad_fin<<<dim3(N_), dim3(256), 0, stream>>>(vacc, ap, c, out, NG_);
    } else {
        float* ap = vacc + vs;
        hipMemsetAsync(d_ws, 0, (vs + as_) * sizeof(float), stream);
        vlad_main<<<dim3(N_ * NG_), dim3(256), 0, stream>>>(x, w, vacc, ap, 0, 0);
        vlad_fin<<<dim3(N_), dim3(256), 0, stream>>>(vacc, ap, c, out, 1);
    }
}